// Round 13
// baseline (143.728 us; speedup 1.0000x reference)
//
#include <hip/hip_runtime.h>
#include <math.h>

#define N_ANCH 10647
#define NA_PAD 10688                   // 167*64, padded+zeroed for gt-side tails
#define N_GT   2048
#define N_OUTC 85
#define PRED_ELEMS (N_ANCH * N_OUTC)   // 904995
#define PRED_V4    (PRED_ELEMS / 4)    // 226248 (3 tail floats)
#define N_CHUNK    42                  // ceil(10647/256)

// virtual IoU tile space (R12-proven geometry): 64-entry chunks, ILP-2
#define ABX 21                         // anchor side: 21 x 512 anchors (2/thread)
#define ABY 32                         //              32 x 64-GT chunks
#define NTILE_A (ABX * ABY)            // 672
#define GBX 4                          // gt side: 4 x 512 GTs (2/thread)
#define GBY 167                        //          167 x 64-anchor chunks
#define NTILE (NTILE_A + GBX * GBY)    // 1340
#define NBLK 512                       // 2 blocks/CU; capacity >= 8/CU -> all co-resident
#define NTHREADS (NBLK * 256)          // 131072

struct WS {
    // ---- memset-zeroed counters, one cache line each (384 B total) ----
    unsigned int sync_b1; unsigned int pad1[31];
    unsigned int sync_b2; unsigned int pad2[31];
    unsigned int sync_t;  unsigned int pad3[31];
    // ---- initialized in-kernel (P0) or write-before-read ----
    float4 ac[NA_PAD];                 // anchor corners (pad zeroed)
    float4 gc[N_GT];                   // gt corners
    unsigned long long akey[N_ANCH];   // packed (iou_bits<<32)|~gt_idx
    unsigned long long gkey[N_GT];     // packed (iou_bits<<32)|~anchor_idx
    float aa[NA_PAD];                  // anchor areas (pad zeroed)
    float ga[N_GT];                    // gt areas
    int cnt_p[N_CHUNK], cnt_n[N_CHUNK];
};
#define MEMSET_BYTES 384

__device__ __forceinline__ float bce(float x, float t) {
    // matches: max(x,0) - x*t + log1p(exp(-|x|))
    return fmaxf(x, 0.0f) - x * t + log1pf(expf(-fabsf(x)));
}

__device__ __forceinline__ unsigned long long packkey(float iou, int idx) {
    return ((unsigned long long)__float_as_uint(iou) << 32) |
           (unsigned)(~(unsigned)idx);
}

// ---------------- single fused kernel (+1 tiny memset dispatch) ----------------
// P0: slice-parallel init (copy, corners, key zero)   [all 512 blocks]
// B1: 512-way arrive+spin (release/acquire, no fence) [all]
// P1: grid-stride IoU over 1340 virtual tiles         [all]
// B2: 512 arrivals; only blocks 0..41 spin            [tail blocks]
// P2: R8-proven tail (labels, 42-way publish/spin, demote-first ranks,
//     column-parallel loss, pre-normalized atomicAdd)
__global__ __launch_bounds__(256) void k_fused(const float* __restrict__ pred,
                                               const float* __restrict__ gtb,
                                               const int* __restrict__ gtl,
                                               const float* __restrict__ priors,
                                               float* __restrict__ out,
                                               WS* __restrict__ ws) {
    __shared__ int sFlg[256];
    __shared__ int wA[4], wB[4];
    __shared__ int wps[4], wns[4];
    __shared__ int sCp[N_CHUNK], sCn[N_CHUNK];
    __shared__ int    sPosI[256];
    __shared__ float4 sPosBox[256];
    __shared__ int    sPosCls[256];
    __shared__ int    sNegI[256];
    __shared__ float  red[12];

    int b = blockIdx.x, t = threadIdx.x, lane = t & 63, wid = t >> 6;
    int gtid = b * 256 + t;

    // ---------------- P0: init ----------------
    for (int idx = gtid; idx < PRED_V4; idx += NTHREADS)
        ((float4*)out)[idx] = ((const float4*)pred)[idx];
    if (gtid == 0) {
        out[PRED_ELEMS - 3] = pred[PRED_ELEMS - 3];
        out[PRED_ELEMS - 2] = pred[PRED_ELEMS - 2];
        out[PRED_ELEMS - 1] = pred[PRED_ELEMS - 1];
        out[PRED_ELEMS] = 0.0f;        // tail atomicAdds into this
    }
    if (gtid < NA_PAD) {
        float4 c = make_float4(0.f, 0.f, 0.f, 0.f);
        float ar = 0.f;
        if (gtid < N_ANCH) {
            float cx = priors[gtid*N_OUTC+0], cy = priors[gtid*N_OUTC+1];
            float w  = priors[gtid*N_OUTC+2], h  = priors[gtid*N_OUTC+3];
            c = make_float4(cx - w*0.5f, cy - h*0.5f, cx + w*0.5f, cy + h*0.5f);
            ar = (c.z - c.x) * (c.w - c.y);
            ws->akey[gtid] = 0ull;
        }
        ws->ac[gtid] = c;
        ws->aa[gtid] = ar;
    }
    if (gtid < N_GT) {
        float4 v = ((const float4*)gtb)[gtid];
        float4 c = make_float4(v.x - v.z*0.5f, v.y - v.w*0.5f,
                               v.x + v.z*0.5f, v.y + v.w*0.5f);
        ws->gc[gtid] = c;
        ws->ga[gtid] = (c.z - c.x) * (c.w - c.y);
        ws->gkey[gtid] = 0ull;
    }

    // ---------------- B1: all 512 blocks ----------------
    __syncthreads();                   // drain this block's P0 stores
    if (t == 0) {
        __hip_atomic_fetch_add(&ws->sync_b1, 1u, __ATOMIC_RELEASE, __HIP_MEMORY_SCOPE_AGENT);
        while (__hip_atomic_load(&ws->sync_b1, __ATOMIC_ACQUIRE, __HIP_MEMORY_SCOPE_AGENT)
               < (unsigned)NBLK)
            __builtin_amdgcn_s_sleep(2);
    }
    __syncthreads();

    // ---------------- P1: grid-stride IoU over virtual tiles ----------------
    for (int vb = b; vb < NTILE; vb += NBLK) {
        if (vb < NTILE_A) {
            // ---- anchor side: 2 anchors/thread vs 64 GTs ----
            int bx = vb % ABX, by = vb / ABX;
            int jbase = by * 64;
            int i0 = bx * 512 + t, i1 = i0 + 256;
            bool v0 = (i0 < N_ANCH), v1 = (i1 < N_ANCH);
            int ri0 = v0 ? i0 : 0, ri1 = v1 ? i1 : 0;
            float4 a0 = ws->ac[ri0]; float aa0 = ws->aa[ri0];
            float4 a1 = ws->ac[ri1]; float aa1 = ws->aa[ri1];
            float I0 = -1.f, S0 = 1.f, I1 = -1.f, S1 = 1.f;
            int bj0 = 0, bj1 = 0;
#pragma unroll 4
            for (int jj = 0; jj < 64; ++jj) {
                float4 g = ws->gc[jbase + jj];
                float ga = ws->ga[jbase + jj];
                float lx = fmaxf(a0.x, g.x), ly = fmaxf(a0.y, g.y);
                float rx = fminf(a0.z, g.z), ry = fminf(a0.w, g.w);
                float In = fmaxf(rx - lx, 0.f) * fmaxf(ry - ly, 0.f);
                float Sn = aa0 + ga;
                bool c = In * S0 > I0 * Sn;    // strict: first index on ties
                I0 = c ? In : I0; S0 = c ? Sn : S0; bj0 = c ? jj : bj0;
                lx = fmaxf(a1.x, g.x); ly = fmaxf(a1.y, g.y);
                rx = fminf(a1.z, g.z); ry = fminf(a1.w, g.w);
                In = fmaxf(rx - lx, 0.f) * fmaxf(ry - ly, 0.f);
                Sn = aa1 + ga;
                c = In * S1 > I1 * Sn;
                I1 = c ? In : I1; S1 = c ? Sn : S1; bj1 = c ? jj : bj1;
            }
            if (v0) atomicMax(&ws->akey[i0], packkey(I0 / (S0 - I0), jbase + bj0));
            if (v1) atomicMax(&ws->akey[i1], packkey(I1 / (S1 - I1), jbase + bj1));
        } else {
            // ---- gt side: 2 GTs/thread vs 64 anchors ----
            int b2 = vb - NTILE_A;
            int bx = b2 % GBX, by = b2 / GBX;
            int ibase = by * 64;               // max 10624; +63 = 10687 < NA_PAD
            int j0 = bx * 512 + t, j1 = j0 + 256;
            float4 g0 = ws->gc[j0]; float ga0 = ws->ga[j0];
            float4 g1 = ws->gc[j1]; float ga1 = ws->ga[j1];
            float I0 = -1.f, S0 = 1.f, I1 = -1.f, S1 = 1.f;
            int bi0 = 0, bi1 = 0;
#pragma unroll 4
            for (int ii = 0; ii < 64; ++ii) {
                float4 a = ws->ac[ibase + ii]; // pad zeroed
                float aa = ws->aa[ibase + ii];
                // pads: In=0 -> 0*Sb > Ib*Sn never true vs held best (Ib>=0,
                // first chunk candidate is always real) -> pads never win.
                float lx = fmaxf(a.x, g0.x), ly = fmaxf(a.y, g0.y);
                float rx = fminf(a.z, g0.z), ry = fminf(a.w, g0.w);
                float In = fmaxf(rx - lx, 0.f) * fmaxf(ry - ly, 0.f);
                float Sn = aa + ga0;
                bool c = In * S0 > I0 * Sn;
                I0 = c ? In : I0; S0 = c ? Sn : S0; bi0 = c ? ii : bi0;
                lx = fmaxf(a.x, g1.x); ly = fmaxf(a.y, g1.y);
                rx = fminf(a.z, g1.z); ry = fminf(a.w, g1.w);
                In = fmaxf(rx - lx, 0.f) * fmaxf(ry - ly, 0.f);
                Sn = aa + ga1;
                c = In * S1 > I1 * Sn;
                I1 = c ? In : I1; S1 = c ? Sn : S1; bi1 = c ? ii : bi1;
            }
            atomicMax(&ws->gkey[j0], packkey(I0 / (S0 - I0), ibase + bi0));
            atomicMax(&ws->gkey[j1], packkey(I1 / (S1 - I1), ibase + bi1));
        }
    }

    // ---------------- B2: 512 arrivals, only tail blocks spin ----------------
    __syncthreads();                   // drain this block's atomics
    if (t == 0) {
        __hip_atomic_fetch_add(&ws->sync_b2, 1u, __ATOMIC_RELEASE, __HIP_MEMORY_SCOPE_AGENT);
    }
    if (b >= N_CHUNK) return;          // 470 blocks exit; no spin traffic
    if (t == 0) {
        while (__hip_atomic_load(&ws->sync_b2, __ATOMIC_ACQUIRE, __HIP_MEMORY_SCOPE_AGENT)
               < (unsigned)NBLK)
            __builtin_amdgcn_s_sleep(2);
    }
    __syncthreads();

    // ---------------- P2: tail (blocks 0..41), R8-proven ----------------
    int base = b * 256;
    sFlg[t] = 0;
    __syncthreads();
    for (int j = t; j < N_GT; j += 256) {
        int ai = (int)(~(unsigned)(ws->gkey[j]));
        int rel = ai - base;
        if ((unsigned)rel < 256u) sFlg[rel] = 1;   // benign same-value races
    }
    __syncthreads();
    int i = base + t;
    int lab = -2;
    if (i < N_ANCH) {
        float amax = __uint_as_float((unsigned)(ws->akey[i] >> 32));
        lab = (amax < 0.3f) ? 0 : ((amax >= 0.7f || sFlg[t]) ? 1 : -1);
    }
    bool f1 = (lab == 1), f0 = (lab == 0);
    unsigned long long b1m = __ballot(f1), b0v = __ballot(f0);
    if (lane == 0) { wA[wid] = __popcll(b1m); wB[wid] = __popcll(b0v); }
    __syncthreads();
    if (t == 0) {
        int cp = wA[0] + wA[1] + wA[2] + wA[3];
        int cn = wB[0] + wB[1] + wB[2] + wB[3];
        __hip_atomic_store(&ws->cnt_p[b], cp, __ATOMIC_RELAXED, __HIP_MEMORY_SCOPE_AGENT);
        __hip_atomic_store(&ws->cnt_n[b], cn, __ATOMIC_RELAXED, __HIP_MEMORY_SCOPE_AGENT);
        __hip_atomic_fetch_add(&ws->sync_t, 1u, __ATOMIC_RELEASE, __HIP_MEMORY_SCOPE_AGENT);
        while (__hip_atomic_load(&ws->sync_t, __ATOMIC_ACQUIRE, __HIP_MEMORY_SCOPE_AGENT)
               < (unsigned)N_CHUNK)
            __builtin_amdgcn_s_sleep(2);
    }
    __syncthreads();
    if (t < N_CHUNK) {
        sCp[t] = __hip_atomic_load(&ws->cnt_p[t], __ATOMIC_ACQUIRE, __HIP_MEMORY_SCOPE_AGENT);
        sCn[t] = __hip_atomic_load(&ws->cnt_n[t], __ATOMIC_ACQUIRE, __HIP_MEMORY_SCOPE_AGENT);
    }
    __syncthreads();
    int npa = 0, nna = 0, pb = 0, nb = 0;
#pragma unroll
    for (int c = 0; c < N_CHUNK; ++c) {
        int cp = sCp[c], cn = sCn[c];
        if (c < b) { pb += cp; nb += cn; }
        npa += cp; nna += cn;
    }
    int excess_pos = (npa > 128) ? (npa - 128) : 0;
    int n_pos_f = npa - excess_pos;
    int n_neg_req = 256 - n_pos_f;
    int excess_neg = (nna > n_neg_req) ? (nna - n_neg_req) : 0;
    int n_neg_f = nna - excess_neg;

    unsigned long long pm = (2ull << lane) - 1ull;   // inclusive mask
    int r1 = __popcll(b1m & pm), r0 = __popcll(b0v & pm);
    if (lane == 0) { wps[wid] = __popcll(b1m); wns[wid] = __popcll(b0v); }
    __syncthreads();
    int p1 = 0, p0 = 0, cpB = 0, cnB = 0;
    for (int w = 0; w < 4; ++w) {
        int v1 = wps[w], v0 = wns[w];
        cpB += v1; cnB += v0;
        if (w < wid) { p1 += v1; p0 += v0; }
    }
    int thp = excess_pos - pb; thp = (thp < 0) ? 0 : thp;
    int thn = excess_neg - nb; thn = (thn < 0) ? 0 : thn;
    if (f1) {
        int L = p1 + r1;                 // 1-based local inclusive rank
        if (L > thp) {
            int slot = L - thp - 1;
            sPosI[slot] = i;
            unsigned am = ~(unsigned)(ws->akey[i]);
            sPosBox[slot] = ((const float4*)gtb)[am];
            sPosCls[slot] = gtl[am] + 5;
        }
    }
    if (f0) {
        int L = p0 + r0;
        if (L > thn) sNegI[L - thn - 1] = i;
    }
    __syncthreads();
    int nP = cpB - thp; nP = (nP < 0) ? 0 : nP;
    int nN = cnB - thn; nN = (nN < 0) ? 0 : nN;

    float acc_a = 0.f, acc_c = 0.f, acc_n = 0.f;
    int nT = nP * N_OUTC;
    for (int u = t; u < nT; u += 256) {
        int pi = u / N_OUTC, col = u - pi * N_OUTC;
        float p = pred[sPosI[pi] * N_OUTC + col];
        if (col < 4) {
            float d = p - ((const float*)&sPosBox[pi])[col];
            acc_a += d * d;
        } else if (col == 4) {
            acc_a += bce(p, 1.0f);
        } else {
            acc_c += bce(p, (col == sPosCls[pi]) ? 1.0f : 0.0f);
        }
    }
    for (int u = t; u < nN; u += 256)
        acc_n += bce(pred[sNegI[u] * N_OUTC + 4], 0.0f);

    for (int o = 32; o; o >>= 1) {
        acc_a += __shfl_down(acc_a, o);
        acc_c += __shfl_down(acc_c, o);
        acc_n += __shfl_down(acc_n, o);
    }
    if (lane == 0) { red[wid] = acc_a; red[4 + wid] = acc_c; red[8 + wid] = acc_n; }
    __syncthreads();
    if (t == 0) {
        float A  = red[0] + red[1] + red[2]  + red[3];
        float C  = red[4] + red[5] + red[6]  + red[7];
        float Nn = red[8] + red[9] + red[10] + red[11];
        float np = fmaxf((float)n_pos_f, 1.0f);
        float nn = fmaxf((float)n_neg_f, 1.0f);
        float contrib = A / np + Nn / nn + C / (np * 80.0f);
        if (contrib != 0.0f) atomicAdd(&out[PRED_ELEMS], contrib);
    }
}

extern "C" void kernel_launch(void* const* d_in, const int* in_sizes, int n_in,
                              void* d_out, int out_size, void* d_ws, size_t ws_size,
                              hipStream_t stream) {
    const float* pred   = (const float*)d_in[0];
    const float* gtb    = (const float*)d_in[1];
    const int*   gtl    = (const int*)d_in[2];
    const float* priors = (const float*)d_in[3];
    float* out = (float*)d_out;
    WS* ws = (WS*)d_ws;

    hipMemsetAsync(d_ws, 0, MEMSET_BYTES, stream);
    k_fused<<<dim3(NBLK), 256, 0, stream>>>(pred, gtb, gtl, priors, out, ws);
}

// Round 14
// 65.447 us; speedup vs baseline: 2.1961x; 2.1961x over previous
//
#include <hip/hip_runtime.h>
#include <math.h>

#define N_ANCH 10647
#define NA_PAD 10688                   // 167*64, padded+zeroed for gt-side tails
#define N_GT   2048
#define N_OUTC 85
#define PRED_ELEMS (N_ANCH * N_OUTC)   // 904995
#define PRED_V4    (PRED_ELEMS / 4)    // 226248 (3 tail floats)
#define N_CHUNK    42                  // ceil(10647/256)

// IoU geometry (best-measured): 64-entry chunks, ILP-2, 1340 blocks
#define ABX 21                         // anchor side: 21 x 512 anchors (2/thread)
#define ABY 32                         //              32 x 64-GT chunks
#define NBLK_A (ABX * ABY)             // 672
#define GBX 4                          // gt side: 4 x 512 GTs (2/thread)
#define GBY 167                        //          167 x 64-anchor chunks
#define NBLK_G (GBX * GBY)             // 668
#define NBLK_IOU (NBLK_A + NBLK_G)     // 1340
#define NBLK_PREP 1024                 // 262144 threads >= PRED_V4

struct WS {
    float4 ac[NA_PAD];                 // anchor corners (pad zeroed)
    float4 gc[N_GT];                   // gt corners
    unsigned long long akey[N_ANCH];   // packed (iou_bits<<32)|~gt_idx
    unsigned long long gkey[N_GT];     // packed (iou_bits<<32)|~anchor_idx
    float aa[NA_PAD];                  // anchor areas (pad zeroed)
    float ga[N_GT];                    // gt areas
    int cnt_p[N_CHUNK], cnt_n[N_CHUNK];
    unsigned int sync;                 // tail barrier counter (zeroed by prep)
};

__device__ __forceinline__ float bce(float x, float t) {
    // matches: max(x,0) - x*t + log1p(exp(-|x|))
    return fmaxf(x, 0.0f) - x * t + log1pf(expf(-fabsf(x)));
}

__device__ __forceinline__ unsigned long long packkey(float iou, int idx) {
    return ((unsigned long long)__float_as_uint(iou) << 32) |
           (unsigned)(~(unsigned)idx);
}

// ---------------- K0: pred->out copy + corners/areas + key/sync zeroing ----------------
__global__ __launch_bounds__(256) void k_prep(const float* __restrict__ pred,
                                              const float* __restrict__ gtb,
                                              const float* __restrict__ priors,
                                              float* __restrict__ out,
                                              WS* __restrict__ ws) {
    int i = blockIdx.x * 256 + threadIdx.x;
    if (i < PRED_V4)
        ((float4*)out)[i] = ((const float4*)pred)[i];
    if (i < NA_PAD) {
        float4 c = make_float4(0.f, 0.f, 0.f, 0.f);
        float ar = 0.f;
        if (i < N_ANCH) {
            float cx = priors[i*N_OUTC+0], cy = priors[i*N_OUTC+1];
            float w  = priors[i*N_OUTC+2], h  = priors[i*N_OUTC+3];
            c = make_float4(cx - w*0.5f, cy - h*0.5f, cx + w*0.5f, cy + h*0.5f);
            ar = (c.z - c.x) * (c.w - c.y);
            ws->akey[i] = 0ull;
        }
        ws->ac[i] = c;
        ws->aa[i] = ar;
    }
    if (i < N_GT) {
        float4 v = ((const float4*)gtb)[i];
        float4 c = make_float4(v.x - v.z*0.5f, v.y - v.w*0.5f,
                               v.x + v.z*0.5f, v.y + v.w*0.5f);
        ws->gc[i] = c;
        ws->ga[i] = (c.z - c.x) * (c.w - c.y);
        ws->gkey[i] = 0ull;
    }
    if (i == 0) {
        out[PRED_ELEMS - 3] = pred[PRED_ELEMS - 3];
        out[PRED_ELEMS - 2] = pred[PRED_ELEMS - 2];
        out[PRED_ELEMS - 1] = pred[PRED_ELEMS - 1];
        out[PRED_ELEMS] = 0.0f;        // tail atomicAdds into this
        ws->sync = 0u;
    }
}

// ---------------- K1: pure IoU reductions ----------------
// Argmax state per slot: (I=inter, S=areaA+areaB, idx); iou = I/(S-I).
// Cross-mult compare (monotone, denominators > 0; I_n*S_b > I_b*S_n is exactly
// iou_n > iou_b since the I_n*I_b terms cancel); one IEEE div per winner
// -> bitwise == reference iou value.
__global__ __launch_bounds__(256) void k_iou(WS* __restrict__ ws) {
    int b = blockIdx.x, t = threadIdx.x;

    if (b < NBLK_A) {
        // ---- anchor side: 2 anchors/thread vs 64 GTs ----
        int bx = b % ABX, by = b / ABX;
        int jbase = by * 64;
        int i0 = bx * 512 + t, i1 = i0 + 256;
        bool v0 = (i0 < N_ANCH), v1 = (i1 < N_ANCH);
        int ri0 = v0 ? i0 : 0, ri1 = v1 ? i1 : 0;
        float4 a0 = ws->ac[ri0]; float aa0 = ws->aa[ri0];
        float4 a1 = ws->ac[ri1]; float aa1 = ws->aa[ri1];
        float I0 = -1.f, S0 = 1.f, I1 = -1.f, S1 = 1.f;
        int bj0 = 0, bj1 = 0;
#pragma unroll 4
        for (int jj = 0; jj < 64; ++jj) {
            float4 g = ws->gc[jbase + jj];
            float ga = ws->ga[jbase + jj];
            float lx = fmaxf(a0.x, g.x), ly = fmaxf(a0.y, g.y);
            float rx = fminf(a0.z, g.z), ry = fminf(a0.w, g.w);
            float In = fmaxf(rx - lx, 0.f) * fmaxf(ry - ly, 0.f);
            float Sn = aa0 + ga;
            bool c = In * S0 > I0 * Sn;        // strict: first index on ties
            I0 = c ? In : I0; S0 = c ? Sn : S0; bj0 = c ? jj : bj0;
            lx = fmaxf(a1.x, g.x); ly = fmaxf(a1.y, g.y);
            rx = fminf(a1.z, g.z); ry = fminf(a1.w, g.w);
            In = fmaxf(rx - lx, 0.f) * fmaxf(ry - ly, 0.f);
            Sn = aa1 + ga;
            c = In * S1 > I1 * Sn;
            I1 = c ? In : I1; S1 = c ? Sn : S1; bj1 = c ? jj : bj1;
        }
        if (v0) atomicMax(&ws->akey[i0], packkey(I0 / (S0 - I0), jbase + bj0));
        if (v1) atomicMax(&ws->akey[i1], packkey(I1 / (S1 - I1), jbase + bj1));
    } else {
        // ---- gt side: 2 GTs/thread vs 64 anchors ----
        int b2 = b - NBLK_A;
        int bx = b2 % GBX, by = b2 / GBX;
        int ibase = by * 64;                   // max 10624; +63 = 10687 < NA_PAD
        int j0 = bx * 512 + t, j1 = j0 + 256;
        float4 g0 = ws->gc[j0]; float ga0 = ws->ga[j0];
        float4 g1 = ws->gc[j1]; float ga1 = ws->ga[j1];
        float I0 = -1.f, S0 = 1.f, I1 = -1.f, S1 = 1.f;
        int bi0 = 0, bi1 = 0;
#pragma unroll 4
        for (int ii = 0; ii < 64; ++ii) {
            float4 a = ws->ac[ibase + ii];     // pad zeroed
            float aa = ws->aa[ibase + ii];
            // pads: In=0 -> 0*Sb > Ib*Sn never true vs a held best (Ib>=0,
            // first chunk candidate is always real) -> pads never win.
            float lx = fmaxf(a.x, g0.x), ly = fmaxf(a.y, g0.y);
            float rx = fminf(a.z, g0.z), ry = fminf(a.w, g0.w);
            float In = fmaxf(rx - lx, 0.f) * fmaxf(ry - ly, 0.f);
            float Sn = aa + ga0;
            bool c = In * S0 > I0 * Sn;
            I0 = c ? In : I0; S0 = c ? Sn : S0; bi0 = c ? ii : bi0;
            lx = fmaxf(a.x, g1.x); ly = fmaxf(a.y, g1.y);
            rx = fminf(a.z, g1.z); ry = fminf(a.w, g1.w);
            In = fmaxf(rx - lx, 0.f) * fmaxf(ry - ly, 0.f);
            Sn = aa + ga1;
            c = In * S1 > I1 * Sn;
            I1 = c ? In : I1; S1 = c ? Sn : S1; bi1 = c ? ii : bi1;
        }
        atomicMax(&ws->gkey[j0], packkey(I0 / (S0 - I0), ibase + bi0));
        atomicMax(&ws->gkey[j1], packkey(I1 / (S1 - I1), ibase + bi1));
    }
}

// ---------------- K2: fused tail with 42-way spin barrier (R8-proven) ----------------
__global__ __launch_bounds__(256) void k_tail2(const float* __restrict__ pred,
                                               const float* __restrict__ gtb,
                                               const int* __restrict__ gtl,
                                               WS* __restrict__ ws,
                                               float* __restrict__ out) {
    __shared__ int sFlg[256];
    __shared__ int wA[4], wB[4];
    __shared__ int wps[4], wns[4];
    __shared__ int sCp[N_CHUNK], sCn[N_CHUNK];
    __shared__ int    sPosI[256];
    __shared__ float4 sPosBox[256];
    __shared__ int    sPosCls[256];
    __shared__ int    sNegI[256];
    __shared__ float  red[12];
    int b = blockIdx.x, t = threadIdx.x, lane = t & 63, wid = t >> 6;
    int base = b * 256;

    // ---- A: own-chunk is_gt_max flags + labels + counts ----
    sFlg[t] = 0;
    __syncthreads();
    for (int j = t; j < N_GT; j += 256) {
        int ai = (int)(~(unsigned)(ws->gkey[j]));
        int rel = ai - base;
        if ((unsigned)rel < 256u) sFlg[rel] = 1;   // benign same-value races
    }
    __syncthreads();
    int i = base + t;
    int lab = -2;
    if (i < N_ANCH) {
        float amax = __uint_as_float((unsigned)(ws->akey[i] >> 32));
        lab = (amax < 0.3f) ? 0 : ((amax >= 0.7f || sFlg[t]) ? 1 : -1);
    }
    bool f1 = (lab == 1), f0 = (lab == 0);
    unsigned long long b1 = __ballot(f1), b0v = __ballot(f0);
    if (lane == 0) { wA[wid] = __popcll(b1); wB[wid] = __popcll(b0v); }
    __syncthreads();
    if (t == 0) {
        int cp = wA[0] + wA[1] + wA[2] + wA[3];
        int cn = wB[0] + wB[1] + wB[2] + wB[3];
        __hip_atomic_store(&ws->cnt_p[b], cp, __ATOMIC_RELAXED, __HIP_MEMORY_SCOPE_AGENT);
        __hip_atomic_store(&ws->cnt_n[b], cn, __ATOMIC_RELAXED, __HIP_MEMORY_SCOPE_AGENT);
        __hip_atomic_fetch_add(&ws->sync, 1u, __ATOMIC_RELEASE, __HIP_MEMORY_SCOPE_AGENT);
        // ---- B: spin until all blocks have published ----
        while (__hip_atomic_load(&ws->sync, __ATOMIC_ACQUIRE, __HIP_MEMORY_SCOPE_AGENT)
               < (unsigned)N_CHUNK)
            __builtin_amdgcn_s_sleep(2);
    }
    __syncthreads();
    if (t < N_CHUNK) {
        sCp[t] = __hip_atomic_load(&ws->cnt_p[t], __ATOMIC_ACQUIRE, __HIP_MEMORY_SCOPE_AGENT);
        sCn[t] = __hip_atomic_load(&ws->cnt_n[t], __ATOMIC_ACQUIRE, __HIP_MEMORY_SCOPE_AGENT);
    }
    __syncthreads();
    int npa = 0, nna = 0, pb = 0, nb = 0;
#pragma unroll
    for (int c = 0; c < N_CHUNK; ++c) {
        int cp = sCp[c], cn = sCn[c];
        if (c < b) { pb += cp; nb += cn; }
        npa += cp; nna += cn;
    }
    int excess_pos = (npa > 128) ? (npa - 128) : 0;
    int n_pos_f = npa - excess_pos;
    int n_neg_req = 256 - n_pos_f;
    int excess_neg = (nna > n_neg_req) ? (nna - n_neg_req) : 0;
    int n_neg_f = nna - excess_neg;

    // ---- C: own-chunk ranks + compaction (survivors = suffix of ranks) ----
    unsigned long long pm = (2ull << lane) - 1ull;   // inclusive mask
    int r1 = __popcll(b1 & pm), r0 = __popcll(b0v & pm);
    if (lane == 0) { wps[wid] = __popcll(b1); wns[wid] = __popcll(b0v); }
    __syncthreads();
    int p1 = 0, p0 = 0, cpB = 0, cnB = 0;
    for (int w = 0; w < 4; ++w) {
        int v1 = wps[w], v0 = wns[w];
        cpB += v1; cnB += v0;
        if (w < wid) { p1 += v1; p0 += v0; }
    }
    int thp = excess_pos - pb; thp = (thp < 0) ? 0 : thp;
    int thn = excess_neg - nb; thn = (thn < 0) ? 0 : thn;
    if (f1) {
        int L = p1 + r1;                 // 1-based local inclusive rank
        if (L > thp) {
            int slot = L - thp - 1;
            sPosI[slot] = i;
            unsigned am = ~(unsigned)(ws->akey[i]);
            sPosBox[slot] = ((const float4*)gtb)[am];
            sPosCls[slot] = gtl[am] + 5;
        }
    }
    if (f0) {
        int L = p0 + r0;
        if (L > thn) sNegI[L - thn - 1] = i;
    }
    __syncthreads();
    int nP = cpB - thp; nP = (nP < 0) ? 0 : nP;
    int nN = cnB - thn; nN = (nN < 0) ? 0 : nN;

    // ---- D: column-parallel loss over block-local survivors ----
    float acc_a = 0.f, acc_c = 0.f, acc_n = 0.f;
    int nT = nP * N_OUTC;
    for (int u = t; u < nT; u += 256) {
        int pi = u / N_OUTC, col = u - pi * N_OUTC;
        float p = pred[sPosI[pi] * N_OUTC + col];
        if (col < 4) {
            float d = p - ((const float*)&sPosBox[pi])[col];
            acc_a += d * d;
        } else if (col == 4) {
            acc_a += bce(p, 1.0f);
        } else {
            acc_c += bce(p, (col == sPosCls[pi]) ? 1.0f : 0.0f);
        }
    }
    for (int u = t; u < nN; u += 256)
        acc_n += bce(pred[sNegI[u] * N_OUTC + 4], 0.0f);

    for (int o = 32; o; o >>= 1) {
        acc_a += __shfl_down(acc_a, o);
        acc_c += __shfl_down(acc_c, o);
        acc_n += __shfl_down(acc_n, o);
    }
    if (lane == 0) { red[wid] = acc_a; red[4 + wid] = acc_c; red[8 + wid] = acc_n; }
    __syncthreads();
    if (t == 0) {
        float A  = red[0] + red[1] + red[2]  + red[3];
        float C  = red[4] + red[5] + red[6]  + red[7];
        float Nn = red[8] + red[9] + red[10] + red[11];
        float np = fmaxf((float)n_pos_f, 1.0f);
        float nn = fmaxf((float)n_neg_f, 1.0f);
        float contrib = A / np + Nn / nn + C / (np * 80.0f);
        if (contrib != 0.0f) atomicAdd(&out[PRED_ELEMS], contrib);
    }
}

extern "C" void kernel_launch(void* const* d_in, const int* in_sizes, int n_in,
                              void* d_out, int out_size, void* d_ws, size_t ws_size,
                              hipStream_t stream) {
    const float* pred   = (const float*)d_in[0];
    const float* gtb    = (const float*)d_in[1];
    const int*   gtl    = (const int*)d_in[2];
    const float* priors = (const float*)d_in[3];
    float* out = (float*)d_out;
    WS* ws = (WS*)d_ws;

    k_prep<<<dim3(NBLK_PREP), 256, 0, stream>>>(pred, gtb, priors, out, ws);
    k_iou<<<dim3(NBLK_IOU), 256, 0, stream>>>(ws);
    k_tail2<<<dim3(N_CHUNK), 256, 0, stream>>>(pred, gtb, gtl, ws, out);
}